// Round 15
// baseline (304.829 us; speedup 1.0000x reference)
//
#include <hip/hip_runtime.h>
#include <hip/hip_bf16.h>
#include <cstdint>
#include <cstddef>

#define B_  4
#define T_  2048
#define D_  1024
#define H_  16
#define DK_ 64
#define M_  (B_ * T_)     // 8192 tokens
#define NT8 (D_ / 64)     // 16 K-tiles of BK=64  (out-proj gemm)
#define NTQ (D_ / 64)     // 16 K-tiles of BK=64  (fused qkv)

typedef __attribute__((ext_vector_type(8))) short bf16x8;   // MFMA A/B frag (4 VGPRs)
typedef __attribute__((ext_vector_type(4))) float f32x4;    // MFMA C/D frag

static __device__ __forceinline__ unsigned short f2bf(float f) {
    __hip_bfloat16 h = __float2bfloat16(f);
    unsigned short u;
    __builtin_memcpy(&u, &h, 2);
    return u;
}

static __device__ __forceinline__ unsigned int pk2bf(float a, float b) {
    __hip_bfloat162 h = __float22bfloat162_rn(make_float2(a, b));
    unsigned int u;
    __builtin_memcpy(&u, &h, 4);
    return u;
}

static __device__ __forceinline__ void gl2lds16(const void* g, void* l) {
    __builtin_amdgcn_global_load_lds(
        (const __attribute__((address_space(1))) unsigned int*)g,
        (__attribute__((address_space(3))) unsigned int*)l,
        16, 0, 0);
}

// ---------------------------------------------------------------------------
// fp32 -> bf16 convert: regions [x | wq | wk | wv | wo] -> contiguous dst.
// ---------------------------------------------------------------------------
__global__ __launch_bounds__(256) void cvt_bf16(
    const float* __restrict__ x,  const float* __restrict__ wq,
    const float* __restrict__ wk, const float* __restrict__ wv,
    const float* __restrict__ wo, unsigned short* __restrict__ dst)
{
    const int idx = blockIdx.x * 256 + threadIdx.x;   // vec4 index
    const float* src;
    int off;
    if (idx < 2097152) { src = x; off = idx; }
    else {
        const int r = (idx - 2097152) >> 18;
        off = (idx - 2097152) & 262143;
        src = (r == 0) ? wq : (r == 1) ? wk : (r == 2) ? wv : wo;
    }
    float4 v = ((const float4*)src)[off];
    ushort4 o;
    o.x = f2bf(v.x); o.y = f2bf(v.y); o.z = f2bf(v.z); o.w = f2bf(v.w);
    ((ushort4*)dst)[idx] = o;
}

// ---------------------------------------------------------------------------
// FUSED QKV GEMM, R15: 128(M)x128(N), BK=64, 8 waves, double-buffered
// As/Bq/Bk/Bv (128 KB -- free: kernel is 1 block/CU by VGPR anyway).
// Halves R14's barrier count (32 vs 64); 48 MFMAs per barrier-pair.
// Subtile: sub = tg*2+ks (tg = row/16, ks = K-half). Per-wave staging
// (8 gl2lds/tile): pre-barrier kt+1 {A ks0/1, Bq ks0/1} -> buf^1 (those
// portions consumed at kt-1); post-lgkm kt+2 {Bk ks0/1, Bv ks0/1} ->
// buf[cur] (reads complete <=~120cy post-barrier, write lands >=200cy --
// R14-validated ordering). FIFO: end-of-tile vmcnt(4) drains exactly tile
// kt+1 (kt-1's post 4 + kt's pre 4); vmcnt(0) at kt=14. Prologue: tile0's
// 8 + tile1's {Bk,Bv} 4, then vmcnt(4). Regs ~206 @ (512,2): no cap spill.
// Grid 512 = 2 exact rounds @1/CU; XCD swizzle (mm fastest).
// ---------------------------------------------------------------------------
__global__ __launch_bounds__(512, 2) void qkv_fused(
    const unsigned short* __restrict__ xb,
    const unsigned short* __restrict__ wqb,
    const unsigned short* __restrict__ wkb,
    const unsigned short* __restrict__ wvb,
    const float* __restrict__ bq,
    const float* __restrict__ bk,
    const float* __restrict__ bv,
    unsigned short* __restrict__ outU)
{
    const int s   = blockIdx.x;           // 0..511
    const int xcd = s & 7;
    const int idx = s >> 3;               // 0..63
    const int mm  = idx & 7;              // m-tile within XCD chunk (fastest)
    const int nn  = idx >> 3;             // 0..7
    const int m0  = (xcd * 8 + mm) * 128;
    const int n0  = nn * 128;

    const int tid  = threadIdx.x;
    const int w    = tid >> 6;
    const int lane = tid & 63;
    const int l15  = lane & 15, g = lane >> 4;
    const int lane8 = lane * 8;
    const int wm4  = (w >> 2) * 4;    // A frag tg base (M half), mi 0..3
    const int wn2  = (w & 3) * 2;     // B frag tg base (N quarter), nj 0..1

    __shared__ __align__(16) unsigned short As[2][16][512];   // 32 KB
    __shared__ __align__(16) unsigned short Bq[2][16][512];   // 32 KB
    __shared__ __align__(16) unsigned short Bk[2][16][512];   // 32 KB
    __shared__ __align__(16) unsigned short Bv[2][16][512];   // 32 KB

    f32x4 aq[4][2], ak[4][2], av[4][2];
#pragma unroll
    for (int i = 0; i < 4; ++i)
#pragma unroll
        for (int j = 0; j < 2; ++j) {
            aq[i][j] = (f32x4){0.f, 0.f, 0.f, 0.f};
            ak[i][j] = (f32x4){0.f, 0.f, 0.f, 0.f};
            av[i][j] = (f32x4){0.f, 0.f, 0.f, 0.f};
        }

    // per-thread global staging addresses; wave w owns subtiles tg=w, ks=0/1
    const unsigned short* aP = xb  + (size_t)(m0 + w * 16 + l15) * D_ + g * 8;
    const unsigned short* qP = wqb + (size_t)(n0 + w * 16 + l15) * D_ + g * 8;
    const unsigned short* kP = wkb + (size_t)(n0 + w * 16 + l15) * D_ + g * 8;
    const unsigned short* vP = wvb + (size_t)(n0 + w * 16 + l15) * D_ + g * 8;

    // ---- prologue: tile0 all 8 roles -> buf0; tile1 {Bk,Bv} -> buf1 ----
    gl2lds16(aP,      &As[0][2 * w    ][0]);
    gl2lds16(aP + 32, &As[0][2 * w + 1][0]);
    gl2lds16(qP,      &Bq[0][2 * w    ][0]);
    gl2lds16(qP + 32, &Bq[0][2 * w + 1][0]);
    gl2lds16(kP,      &Bk[0][2 * w    ][0]);
    gl2lds16(kP + 32, &Bk[0][2 * w + 1][0]);
    gl2lds16(vP,      &Bv[0][2 * w    ][0]);
    gl2lds16(vP + 32, &Bv[0][2 * w + 1][0]);
    gl2lds16(kP + 64, &Bk[1][2 * w    ][0]);
    gl2lds16(kP + 96, &Bk[1][2 * w + 1][0]);
    gl2lds16(vP + 64, &Bv[1][2 * w    ][0]);
    gl2lds16(vP + 96, &Bv[1][2 * w + 1][0]);
    asm volatile("s_waitcnt vmcnt(4)" ::: "memory");   // tile 0 landed
    __builtin_amdgcn_s_barrier();

    bf16x8 ap[4][2], fq[2][2], fk[2][2], fv[2][2];

    for (int kt = 0; kt < NTQ; ++kt) {
        const int cur = kt & 1;
        const int ko  = kt * 64;

        // ds_read 20 frags from buf[cur]
#pragma unroll
        for (int mi = 0; mi < 4; ++mi)
#pragma unroll
            for (int ks = 0; ks < 2; ++ks)
                ap[mi][ks] = *(const bf16x8*)&As[cur][(wm4 + mi) * 2 + ks][lane8];
#pragma unroll
        for (int nj = 0; nj < 2; ++nj)
#pragma unroll
            for (int ks = 0; ks < 2; ++ks) {
                fq[nj][ks] = *(const bf16x8*)&Bq[cur][(wn2 + nj) * 2 + ks][lane8];
                fk[nj][ks] = *(const bf16x8*)&Bk[cur][(wn2 + nj) * 2 + ks][lane8];
                fv[nj][ks] = *(const bf16x8*)&Bv[cur][(wn2 + nj) * 2 + ks][lane8];
            }

        // pre-barrier: stage kt+1 {A, Bq} -> buf^1 (portions consumed at kt-1)
        if (kt + 1 < NTQ) {
            gl2lds16(aP + ko + 64, &As[cur ^ 1][2 * w    ][0]);
            gl2lds16(aP + ko + 96, &As[cur ^ 1][2 * w + 1][0]);
            gl2lds16(qP + ko + 64, &Bq[cur ^ 1][2 * w    ][0]);
            gl2lds16(qP + ko + 96, &Bq[cur ^ 1][2 * w + 1][0]);
        }

        __builtin_amdgcn_s_barrier();
        asm volatile("s_waitcnt lgkmcnt(0)" ::: "memory");

        // post-lgkm: stage kt+2 {Bk,Bv} -> buf[cur] (R14-validated ordering)
        if (kt + 2 < NTQ) {
            gl2lds16(kP + ko + 128, &Bk[cur][2 * w    ][0]);
            gl2lds16(kP + ko + 160, &Bk[cur][2 * w + 1][0]);
            gl2lds16(vP + ko + 128, &Bv[cur][2 * w    ][0]);
            gl2lds16(vP + ko + 160, &Bv[cur][2 * w + 1][0]);
        }

        __builtin_amdgcn_s_setprio(1);
#pragma unroll
        for (int mi = 0; mi < 4; ++mi)
#pragma unroll
            for (int nj = 0; nj < 2; ++nj) {
#pragma unroll
                for (int ks = 0; ks < 2; ++ks)
                    aq[mi][nj] = __builtin_amdgcn_mfma_f32_16x16x32_bf16(
                        fq[nj][ks], ap[mi][ks], aq[mi][nj], 0, 0, 0);
#pragma unroll
                for (int ks = 0; ks < 2; ++ks)
                    ak[mi][nj] = __builtin_amdgcn_mfma_f32_16x16x32_bf16(
                        fk[nj][ks], ap[mi][ks], ak[mi][nj], 0, 0, 0);
#pragma unroll
                for (int ks = 0; ks < 2; ++ks)
                    av[mi][nj] = __builtin_amdgcn_mfma_f32_16x16x32_bf16(
                        ap[mi][ks], fv[nj][ks], av[mi][nj], 0, 0, 0);
            }
        __builtin_amdgcn_s_setprio(0);

        if (kt < NTQ - 2)       asm volatile("s_waitcnt vmcnt(4)" ::: "memory");
        else if (kt == NTQ - 2) asm volatile("s_waitcnt vmcnt(0)" ::: "memory");
        __builtin_amdgcn_s_barrier();
    }

    // ---- epilogue: Q (scaled), K -> [bh][t][dk]; V -> V^T [bh][dk][t] ----
    const int mbase = m0 + (w >> 2) * 64;
    const int nbase = n0 + (w & 3) * 32;
    const size_t BTD = (size_t)B_ * T_ * D_;
    const float osc = 0.125f * 1.44269504f;

#pragma unroll
    for (int nj = 0; nj < 2; ++nj) {
        const int ch0 = nbase + nj * 16 + g * 4;
        const int hh = ch0 >> 6, dk0 = ch0 & 63;
        const float4 bbq = *(const float4*)(bq + ch0);
        const float4 bbk = *(const float4*)(bk + ch0);
#pragma unroll
        for (int mi = 0; mi < 4; ++mi) {
            const int tok = mbase + mi * 16 + l15;
            const int b = tok >> 11, t = tok & (T_ - 1);
            const size_t base = ((size_t)((b * H_ + hh) * T_ + t)) * DK_ + dk0;
            ushort4 rq, rk;
            rq.x = f2bf((aq[mi][nj][0] + bbq.x) * osc);
            rq.y = f2bf((aq[mi][nj][1] + bbq.y) * osc);
            rq.z = f2bf((aq[mi][nj][2] + bbq.z) * osc);
            rq.w = f2bf((aq[mi][nj][3] + bbq.w) * osc);
            rk.x = f2bf(ak[mi][nj][0] + bbk.x);
            rk.y = f2bf(ak[mi][nj][1] + bbk.y);
            rk.z = f2bf(ak[mi][nj][2] + bbk.z);
            rk.w = f2bf(ak[mi][nj][3] + bbk.w);
            *(ushort4*)(outU + base) = rq;
            *(ushort4*)(outU + BTD + base) = rk;
        }
    }
    {
        unsigned short* outv = outU + 2 * BTD;
#pragma unroll
        for (int nj = 0; nj < 2; ++nj) {
            const int ch = nbase + nj * 16 + l15;
            const int hh = ch >> 6, dk = ch & 63;
            const float bbv = bv[ch];
#pragma unroll
            for (int mi = 0; mi < 4; ++mi) {
                const int tok0 = mbase + mi * 16 + g * 4;
                const int b = tok0 >> 11, t0 = tok0 & (T_ - 1);
                ushort4 r;
                r.x = f2bf(av[mi][nj][0] + bbv);
                r.y = f2bf(av[mi][nj][1] + bbv);
                r.z = f2bf(av[mi][nj][2] + bbv);
                r.w = f2bf(av[mi][nj][3] + bbv);
                *(ushort4*)(outv + ((size_t)((b * H_ + hh) * DK_ + dk)) * T_ + t0) = r;
            }
        }
    }
}

// ---------------------------------------------------------------------------
// 256(M)x128(N) BK=64 MFMA GEMM (R3 structure, frozen) — out-proj (mode 1).
// ---------------------------------------------------------------------------
__global__ __launch_bounds__(512, 2) void gemm8p(
    const unsigned short* __restrict__ Amat,
    const unsigned short* __restrict__ w0,
    const unsigned short* __restrict__ w1,
    const unsigned short* __restrict__ w2,
    const float* __restrict__ b0,
    const float* __restrict__ b1,
    const float* __restrict__ b2,
    unsigned short* __restrict__ outU,
    float* __restrict__ outF,
    const int mode)
{
    const int s   = blockIdx.x;
    const int xcd = s & 7;
    const int idx = s >> 3;
    const int mm  = idx & 3;
    const int ns  = idx >> 2;
    const int sel = (mode == 0) ? (ns >> 3) : 3;
    const int nn  = (mode == 0) ? (ns & 7) : ns;
    const int m0  = (xcd * 4 + mm) * 256;
    const int n0  = nn * 128;

    const unsigned short* Bmat = (sel == 0) ? w0 : (sel == 1) ? w1 : w2;
    const float* bias          = (sel == 0) ? b0 : (sel == 1) ? b1 : b2;
    const bool selV = (sel == 2);

    const int tid  = threadIdx.x;
    const int w    = tid >> 6;
    const int lane = tid & 63;
    const int l15  = lane & 15, g = lane >> 4;
    const int lane8 = lane * 8;
    const int wm8  = (w >> 2) * 8;
    const int wn2  = (w & 3) * 2;

    __shared__ __align__(16) unsigned short As[2][32][512];   // 64 KB
    __shared__ __align__(16) unsigned short Bs[2][16][512];   // 32 KB

    f32x4 acc[8][2];
#pragma unroll
    for (int i = 0; i < 8; ++i)
#pragma unroll
        for (int j = 0; j < 2; ++j) acc[i][j] = (f32x4){0.f, 0.f, 0.f, 0.f};

    const unsigned short* aP[4];
#pragma unroll
    for (int j = 0; j < 4; ++j)
        aP[j] = Amat + (size_t)(m0 + (w >> 1) * 16 + 64 * j + l15) * D_
                     + (w & 1) * 32 + g * 8;
    const unsigned short* bP[2];
#pragma unroll
    for (int jb = 0; jb < 2; ++jb)
        bP[jb] = Bmat + (size_t)(n0 + w * 16 + l15) * D_ + jb * 32 + g * 8;

#pragma unroll
    for (int j = 0; j < 4; ++j) gl2lds16(aP[j], &As[0][w + 8 * j][0]);
    gl2lds16(bP[0], &Bs[0][2 * w    ][0]);
    gl2lds16(bP[1], &Bs[0][2 * w + 1][0]);
    gl2lds16(aP[0] + 64, &As[1][w     ][0]);
    gl2lds16(aP[2] + 64, &As[1][w + 16][0]);
    gl2lds16(bP[0] + 64, &Bs[1][2 * w    ][0]);
    gl2lds16(bP[1] + 64, &Bs[1][2 * w + 1][0]);
    asm volatile("s_waitcnt vmcnt(4)" ::: "memory");
    __builtin_amdgcn_s_barrier();

    bf16x8 bfr[2][2];
    bf16x8 ap[4][2];

    for (int kt = 0; kt < NT8; ++kt) {
        const int cur = kt & 1;
        const int ko  = kt * 64;

#pragma unroll
        for (int nj = 0; nj < 2; ++nj)
#pragma unroll
            for (int ks = 0; ks < 2; ++ks)
                bfr[nj][ks] = *(const bf16x8*)&Bs[cur][(wn2 + nj) * 2 + ks][lane8];
#pragma unroll
        for (int mi = 0; mi < 4; ++mi)
#pragma unroll
            for (int ks = 0; ks < 2; ++ks)
                ap[mi][ks] = *(const bf16x8*)&As[cur][(wm8 + mi) * 2 + ks][lane8];
        if (kt + 1 < NT8) {
            gl2lds16(aP[1] + ko + 64, &As[cur ^ 1][w + 8 ][0]);
            gl2lds16(aP[3] + ko + 64, &As[cur ^ 1][w + 24][0]);
        }
        __builtin_amdgcn_s_barrier();
        asm volatile("s_waitcnt lgkmcnt(0)" ::: "memory");
        __builtin_amdgcn_s_setprio(1);
        if (!selV) {
#pragma unroll
            for (int mi = 0; mi < 4; ++mi)
#pragma unroll
                for (int nj = 0; nj < 2; ++nj) {
                    acc[mi][nj] = __builtin_amdgcn_mfma_f32_16x16x32_bf16(
                        bfr[nj][0], ap[mi][0], acc[mi][nj], 0, 0, 0);
                    acc[mi][nj] = __builtin_amdgcn_mfma_f32_16x16x32_bf16(
                        bfr[nj][1], ap[mi][1], acc[mi][nj], 0, 0, 0);
                }
        } else {
#pragma unroll
            for (int mi = 0; mi < 4; ++mi)
#pragma unroll
                for (int nj = 0; nj < 2; ++nj) {
                    acc[mi][nj] = __builtin_amdgcn_mfma_f32_16x16x32_bf16(
                        ap[mi][0], bfr[nj][0], acc[mi][nj], 0, 0, 0);
                    acc[mi][nj] = __builtin_amdgcn_mfma_f32_16x16x32_bf16(
                        ap[mi][1], bfr[nj][1], acc[mi][nj], 0, 0, 0);
                }
        }
        __builtin_amdgcn_s_setprio(0);
        __builtin_amdgcn_s_barrier();

#pragma unroll
        for (int mi = 0; mi < 4; ++mi)
#pragma unroll
            for (int ks = 0; ks < 2; ++ks)
                ap[mi][ks] = *(const bf16x8*)&As[cur][(wm8 + 4 + mi) * 2 + ks][lane8];
        if (kt + 2 < NT8) {
            gl2lds16(aP[0] + ko + 128, &As[cur][w     ][0]);
            gl2lds16(aP[2] + ko + 128, &As[cur][w + 16][0]);
            gl2lds16(bP[0] + ko + 128, &Bs[cur][2 * w    ][0]);
            gl2lds16(bP[1] + ko + 128, &Bs[cur][2 * w + 1][0]);
        }
        __builtin_amdgcn_s_barrier();
        asm volatile("s_waitcnt lgkmcnt(0)" ::: "memory");
        __builtin_amdgcn_s_setprio(1);
        if (!selV) {
#pragma unroll
            for (int mi = 0; mi < 4; ++mi)
#pragma unroll
                for (int nj = 0; nj < 2; ++nj) {
                    acc[4 + mi][nj] = __builtin_amdgcn_mfma_f32_16x16x32_bf16(
                        bfr[nj][0], ap[mi][0], acc[4 + mi][nj], 0, 0, 0);
                    acc[4 + mi][nj] = __builtin_amdgcn_mfma_f32_16x16x32_bf16(
                        bfr[nj][1], ap[mi][1], acc[4 + mi][nj], 0, 0, 0);
                }
        } else {
#pragma unroll
            for (int mi = 0; mi < 4; ++mi)
#pragma unroll
                for (int nj = 0; nj < 2; ++nj) {
                    acc[4 + mi][nj] = __builtin_amdgcn_mfma_f32_16x16x32_bf16(
                        ap[mi][0], bfr[nj][0], acc[4 + mi][nj], 0, 0, 0);
                    acc[4 + mi][nj] = __builtin_amdgcn_mfma_f32_16x16x32_bf16(
                        ap[mi][1], bfr[nj][1], acc[4 + mi][nj], 0, 0, 0);
                }
        }
        __builtin_amdgcn_s_setprio(0);
        if (kt < NT8 - 2)       asm volatile("s_waitcnt vmcnt(4)" ::: "memory");
        else if (kt == NT8 - 2) asm volatile("s_waitcnt vmcnt(0)" ::: "memory");
        __builtin_amdgcn_s_barrier();
    }

    const int mbase = m0 + (w >> 2) * 128;
    const int nbase = n0 + (w & 3) * 32;
    const size_t BTD = (size_t)B_ * T_ * D_;

    if (mode == 1) {
#pragma unroll
        for (int nj = 0; nj < 2; ++nj) {
            const int ch0 = nbase + nj * 16 + g * 4;
            const float4 bb = *(const float4*)(bias + ch0);
#pragma unroll
            for (int mi = 0; mi < 8; ++mi) {
                const int tok = mbase + mi * 16 + l15;
                float4 r;
                r.x = acc[mi][nj][0] + bb.x;
                r.y = acc[mi][nj][1] + bb.y;
                r.z = acc[mi][nj][2] + bb.z;
                r.w = acc[mi][nj][3] + bb.w;
                *(float4*)(outF + (size_t)tok * D_ + ch0) = r;
            }
        }
    } else if (!selV) {
        unsigned short* outp = outU + (size_t)sel * BTD;
        const float osc = (sel == 0) ? 0.125f * 1.44269504f : 1.0f;
#pragma unroll
        for (int nj = 0; nj < 2; ++nj) {
            const int ch0 = nbase + nj * 16 + g * 4;
            const int hh = ch0 >> 6, dk0 = ch0 & 63;
            const float4 bb = *(const float4*)(bias + ch0);
#pragma unroll
            for (int mi = 0; mi < 8; ++mi) {
                const int tok = mbase + mi * 16 + l15;
                const int b = tok >> 11, t = tok & (T_ - 1);
                ushort4 r;
                r.x = f2bf((acc[mi][nj][0] + bb.x) * osc);
                r.y = f2bf((acc[mi][nj][1] + bb.y) * osc);
                r.z = f2bf((acc[mi][nj][2] + bb.z) * osc);
                r.w = f2bf((acc[mi][nj][3] + bb.w) * osc);
                *(ushort4*)(outp + ((size_t)((b * H_ + hh) * T_ + t)) * DK_ + dk0) = r;
            }
        }
    } else {
        unsigned short* outp = outU + 2 * BTD;
#pragma unroll
        for (int nj = 0; nj < 2; ++nj) {
            const int ch = nbase + nj * 16 + l15;
            const int hh = ch >> 6, dk = ch & 63;
            const float bbv = bias[ch];
#pragma unroll
            for (int mi = 0; mi < 8; ++mi) {
                const int tok0 = mbase + mi * 16 + g * 4;
                const int b = tok0 >> 11, t0 = tok0 & (T_ - 1);
                ushort4 r;
                r.x = f2bf(acc[mi][nj][0] + bbv);
                r.y = f2bf(acc[mi][nj][1] + bbv);
                r.z = f2bf(acc[mi][nj][2] + bbv);
                r.w = f2bf(acc[mi][nj][3] + bbv);
                *(ushort4*)(outp + ((size_t)((b * H_ + hh) * DK_ + dk)) * T_ + t0) = r;
            }
        }
    }
}

// ---------------------------------------------------------------------------
// MFMA flash attention — EXACT R8 body (measured 107.7 us; frozen).
// ---------------------------------------------------------------------------
__global__ __launch_bounds__(256) void attn(
    const unsigned short* __restrict__ qg, const unsigned short* __restrict__ kg,
    const unsigned short* __restrict__ vtg,
    unsigned short* __restrict__ yh)
{
    const int s    = blockIdx.x;          // 0..2047
    const int xcd  = s & 7;
    const int t_   = s >> 3;              // 0..255
    const int bhl  = t_ >> 5;             // 0..7
    const int j    = t_ & 31;
    const int bh   = xcd * 8 + bhl;
    const int x    = 31 - j;              // heavy-first
    const int h    = bh & (H_ - 1);
    const int b    = bh >> 4;
    const int tq0  = x * 64;
    const int nCh  = x + 1;               // keys 0..tq0+63, 64-wide chunks

    const int tid  = threadIdx.x;
    const int w    = tid >> 6;
    const int lane = tid & 63;
    const int l15  = lane & 15;
    const int g    = lane >> 4;

    const size_t base = (size_t)bh * T_ * DK_;
    const unsigned short* Qb  = qg  + base;   // [t][dk], pre-scaled
    const unsigned short* Kb  = kg  + base;   // [t][dk]
    const unsigned short* Vtb = vtg + base;   // [dk][t]

    __shared__ __align__(16) unsigned short Kf[8][512];     // 8 KB
    __shared__ __align__(16) unsigned short Vf[8][512];     // 8 KB
    __shared__ __align__(16) unsigned short Pb[4][16][68];  // 8.7 KB

    const int q0w = tq0 + w * 16;
    const int tq  = q0w + l15;

    bf16x8 qf0 = *(const bf16x8*)(Qb + (size_t)tq * DK_ + g * 8);
    bf16x8 qf1 = *(const bf16x8*)(Qb + (size_t)tq * DK_ + 32 + g * 8);

    bf16x8 ones;
#pragma unroll
    for (int jj = 0; jj < 8; ++jj) ones[jj] = (short)0x3F80;

    f32x4 o[4];
#pragma unroll
    for (int i = 0; i < 4; ++i) o[i] = (f32x4){0.f, 0.f, 0.f, 0.f};
    f32x4 lacc = {0.f, 0.f, 0.f, 0.f};

    const unsigned short* kSrc = Kb + (size_t)(w * 16 + l15) * DK_ + g * 8;
    const unsigned short* vSrc = Vtb + (size_t)(w * 16 + l15) * T_ + g * 8;

    bf16x8 kr0 = *(const bf16x8*)(kSrc);
    bf16x8 kr1 = *(const bf16x8*)(kSrc + 32);
    bf16x8 vr0 = *(const bf16x8*)(vSrc);
    bf16x8 vr1 = *(const bf16x8*)(vSrc + 32);

    for (int ch = 0; ch < nCh; ++ch) {
        const int s0 = ch * 64;
        __syncthreads();                       // previous chunk fully consumed
        *(bf16x8*)&Kf[2 * w    ][lane * 8] = kr0;
        *(bf16x8*)&Kf[2 * w + 1][lane * 8] = kr1;
        *(bf16x8*)&Vf[2 * w    ][lane * 8] = vr0;
        *(bf16x8*)&Vf[2 * w + 1][lane * 8] = vr1;
        if (ch + 1 < nCh) {                    // loads stay in flight across barrier
            const size_t ko = (size_t)(ch + 1) * 64 * DK_;
            const int    vo = (ch + 1) * 64;
            kr0 = *(const bf16x8*)(kSrc + ko);
            kr1 = *(const bf16x8*)(kSrc + ko + 32);
            vr0 = *(const bf16x8*)(vSrc + vo);
            vr1 = *(const bf16x8*)(vSrc + vo + 32);
        }
        __syncthreads();                       // staged data visible

#pragma unroll
        for (int st = 0; st < 4; ++st) {
            const int sbase = s0 + st * 16;
            const bool live = (sbase <= q0w + 15);
            unsigned int pkl, pkh;
            if (live) {
                bf16x8 a0 = *(const bf16x8*)&Kf[st * 2 + 0][lane * 8];
                bf16x8 a1 = *(const bf16x8*)&Kf[st * 2 + 1][lane * 8];
                f32x4 sacc = {0.f, 0.f, 0.f, 0.f};
                sacc = __builtin_amdgcn_mfma_f32_16x16x32_bf16(a0, qf0, sacc, 0, 0, 0);
                sacc = __builtin_amdgcn_mfma_f32_16x16x32_bf16(a1, qf1, sacc, 0, 0, 0);
                float p0, p1, p2, p3;
                if (sbase + 15 > q0w) {        // diagonal tile: per-entry mask
                    p0 = (sbase + g * 4 + 0 <= tq) ? exp2f(sacc[0]) : 0.f;
                    p1 = (sbase + g * 4 + 1 <= tq) ? exp2f(sacc[1]) : 0.f;
                    p2 = (sbase + g * 4 + 2 <= tq) ? exp2f(sacc[2]) : 0.f;
                    p3 = (sbase + g * 4 + 3 <= tq) ? exp2f(sacc[3]) : 0.f;
                } else {                       // fully unmasked
                    p0 = exp2f(sacc[0]); p1 = exp2f(sacc[1]);
                    p2 = exp2f(sacc[2]); p3 = exp2f(sacc[3]);
                }
                pkl = pk2bf(p0, p1);
                pkh = pk2bf(p2, p3);
            } else {
                pkl = 0; pkh = 0;
            }
            uint2 pk; pk.x = pkl; pk.y = pkh;
            *(uint2*)&Pb[w][l15][st * 16 + g * 4] = pk;     // P[q][s], s-contig
        }

        bf16x8 pf0 = *(const bf16x8*)&Pb[w][l15][g * 8];        // k = s 0..31
        bf16x8 pf1 = *(const bf16x8*)&Pb[w][l15][32 + g * 8];   // k = s 32..63
        __builtin_amdgcn_s_setprio(1);
        lacc = __builtin_amdgcn_mfma_f32_16x16x32_bf16(ones, pf0, lacc, 0, 0, 0);
        lacc = __builtin_amdgcn_mfma_f32_16x16x32_bf16(ones, pf1, lacc, 0, 0, 0);
#pragma unroll
        for (int dt = 0; dt < 4; ++dt) {
            bf16x8 v0 = *(const bf16x8*)&Vf[dt * 2 + 0][lane * 8];
            bf16x8 v1 = *(const bf16x8*)&Vf[dt * 2 + 1][lane * 8];
            o[dt] = __builtin_amdgcn_mfma_f32_16x16x32_bf16(v0, pf0, o[dt], 0, 0, 0);
            o[dt] = __builtin_amdgcn_mfma_f32_16x16x32_bf16(v1, pf1, o[dt], 0, 0, 0);
        }
        __builtin_amdgcn_s_setprio(0);
    }

    // normalize and write yh bf16 directly (always single-pass)
    const float inv = 1.f / lacc[0];
    unsigned short* yrow = yh + ((size_t)(b * T_ + tq)) * D_ + h * DK_;
#pragma unroll
    for (int dt = 0; dt < 4; ++dt) {
        ushort4 r;
        r.x = f2bf(o[dt][0] * inv); r.y = f2bf(o[dt][1] * inv);
        r.z = f2bf(o[dt][2] * inv); r.w = f2bf(o[dt][3] * inv);
        *(ushort4*)(yrow + dt * 16 + g * 4) = r;
    }
}

// ---------------------------------------------------------------------------
extern "C" void kernel_launch(void* const* d_in, const int* in_sizes, int n_in,
                              void* d_out, int out_size, void* d_ws, size_t ws_size,
                              hipStream_t stream) {
    const float* x  = (const float*)d_in[0];
    const float* wq = (const float*)d_in[1];
    const float* bq = (const float*)d_in[2];
    const float* wk = (const float*)d_in[3];
    const float* bk = (const float*)d_in[4];
    const float* wv = (const float*)d_in[5];
    const float* bv = (const float*)d_in[6];
    const float* wo = (const float*)d_in[7];
    const float* bo = (const float*)d_in[8];
    float* out = (float*)d_out;

    const size_t BTD = (size_t)B_ * T_ * D_;          // 8388608
    const size_t WSZ = (size_t)D_ * D_;               // 1048576
    unsigned short* xb  = (unsigned short*)d_ws;      // [x | wq | wk | wv | wo] bf16
    unsigned short* wqb = xb  + BTD;
    unsigned short* wkb = wqb + WSZ;
    unsigned short* wvb = wkb + WSZ;
    unsigned short* wob = wvb + WSZ;
    unsigned short* qb  = wob + WSZ;                  // q | k | vt bf16
    unsigned short* kb  = qb  + BTD;
    unsigned short* vtb = kb  + BTD;
    unsigned short* yhb = vtb + BTD;                  // yh bf16 [B,T,D]

    cvt_bf16<<<dim3(12288), 256, 0, stream>>>(x, wq, wk, wv, wo, xb);

    // fused QKV: 8 xcd x 8 m x 8 n = 512 blocks = 2 exact rounds @1/CU
    qkv_fused<<<dim3(512), 512, 0, stream>>>(
        xb, wqb, wkb, wvb, bq, bk, bv, qb);

    // attn: 2048 blocks (32 per bh), XCD-pinned, heavy-first, single-pass
    attn<<<dim3(2048), 256, 0, stream>>>(qb, kb, vtb, yhb);

    // out-proj: 8 x 4 x 8 = 256 blocks = exactly 1 round (R3 gemm, frozen)
    gemm8p<<<dim3(256), 512, 0, stream>>>(
        yhb, wob, wob, wob, bo, bo, bo, (unsigned short*)nullptr, out, 1);
}

// Round 16
// 281.282 us; speedup vs baseline: 1.0837x; 1.0837x over previous
//
#include <hip/hip_runtime.h>
#include <hip/hip_bf16.h>
#include <cstdint>
#include <cstddef>

#define B_  4
#define T_  2048
#define D_  1024
#define H_  16
#define DK_ 64
#define M_  (B_ * T_)     // 8192 tokens
#define NT8 (D_ / 64)     // 16 K-tiles of BK=64  (out-proj gemm)
#define NTQ (D_ / 64)     // 16 K-tiles of BK=64  (fused qkv)

typedef __attribute__((ext_vector_type(8))) short bf16x8;   // MFMA A/B frag (4 VGPRs)
typedef __attribute__((ext_vector_type(4))) float f32x4;    // MFMA C/D frag

static __device__ __forceinline__ unsigned short f2bf(float f) {
    __hip_bfloat16 h = __float2bfloat16(f);
    unsigned short u;
    __builtin_memcpy(&u, &h, 2);
    return u;
}

static __device__ __forceinline__ unsigned int pk2bf(float a, float b) {
    __hip_bfloat162 h = __float22bfloat162_rn(make_float2(a, b));
    unsigned int u;
    __builtin_memcpy(&u, &h, 4);
    return u;
}

static __device__ __forceinline__ void gl2lds16(const void* g, void* l) {
    __builtin_amdgcn_global_load_lds(
        (const __attribute__((address_space(1))) unsigned int*)g,
        (__attribute__((address_space(3))) unsigned int*)l,
        16, 0, 0);
}

// ---------------------------------------------------------------------------
// fp32 -> bf16 convert: regions [x | wq | wk | wv | wo] -> contiguous dst.
// ---------------------------------------------------------------------------
__global__ __launch_bounds__(256) void cvt_bf16(
    const float* __restrict__ x,  const float* __restrict__ wq,
    const float* __restrict__ wk, const float* __restrict__ wv,
    const float* __restrict__ wo, unsigned short* __restrict__ dst)
{
    const int idx = blockIdx.x * 256 + threadIdx.x;   // vec4 index
    const float* src;
    int off;
    if (idx < 2097152) { src = x; off = idx; }
    else {
        const int r = (idx - 2097152) >> 18;
        off = (idx - 2097152) & 262143;
        src = (r == 0) ? wq : (r == 1) ? wk : (r == 2) ? wv : wo;
    }
    float4 v = ((const float4*)src)[off];
    ushort4 o;
    o.x = f2bf(v.x); o.y = f2bf(v.y); o.z = f2bf(v.z); o.w = f2bf(v.w);
    ((ushort4*)dst)[idx] = o;
}

// ---------------------------------------------------------------------------
// FUSED QKV GEMM (R15 structure, measured = R14; frozen): 128x128, BK=64,
// 8 waves, dbuf As/Bq/Bk/Bv (128 KB), counted vmcnt + setprio, XCD swizzle.
// ---------------------------------------------------------------------------
__global__ __launch_bounds__(512, 2) void qkv_fused(
    const unsigned short* __restrict__ xb,
    const unsigned short* __restrict__ wqb,
    const unsigned short* __restrict__ wkb,
    const unsigned short* __restrict__ wvb,
    const float* __restrict__ bq,
    const float* __restrict__ bk,
    const float* __restrict__ bv,
    unsigned short* __restrict__ outU)
{
    const int s   = blockIdx.x;           // 0..511
    const int xcd = s & 7;
    const int idx = s >> 3;               // 0..63
    const int mm  = idx & 7;              // m-tile within XCD chunk (fastest)
    const int nn  = idx >> 3;             // 0..7
    const int m0  = (xcd * 8 + mm) * 128;
    const int n0  = nn * 128;

    const int tid  = threadIdx.x;
    const int w    = tid >> 6;
    const int lane = tid & 63;
    const int l15  = lane & 15, g = lane >> 4;
    const int lane8 = lane * 8;
    const int wm4  = (w >> 2) * 4;    // A frag tg base (M half), mi 0..3
    const int wn2  = (w & 3) * 2;     // B frag tg base (N quarter), nj 0..1

    __shared__ __align__(16) unsigned short As[2][16][512];   // 32 KB
    __shared__ __align__(16) unsigned short Bq[2][16][512];   // 32 KB
    __shared__ __align__(16) unsigned short Bk[2][16][512];   // 32 KB
    __shared__ __align__(16) unsigned short Bv[2][16][512];   // 32 KB

    f32x4 aq[4][2], ak[4][2], av[4][2];
#pragma unroll
    for (int i = 0; i < 4; ++i)
#pragma unroll
        for (int j = 0; j < 2; ++j) {
            aq[i][j] = (f32x4){0.f, 0.f, 0.f, 0.f};
            ak[i][j] = (f32x4){0.f, 0.f, 0.f, 0.f};
            av[i][j] = (f32x4){0.f, 0.f, 0.f, 0.f};
        }

    // per-thread global staging addresses; wave w owns subtiles tg=w, ks=0/1
    const unsigned short* aP = xb  + (size_t)(m0 + w * 16 + l15) * D_ + g * 8;
    const unsigned short* qP = wqb + (size_t)(n0 + w * 16 + l15) * D_ + g * 8;
    const unsigned short* kP = wkb + (size_t)(n0 + w * 16 + l15) * D_ + g * 8;
    const unsigned short* vP = wvb + (size_t)(n0 + w * 16 + l15) * D_ + g * 8;

    // ---- prologue: tile0 all 8 roles -> buf0; tile1 {Bk,Bv} -> buf1 ----
    gl2lds16(aP,      &As[0][2 * w    ][0]);
    gl2lds16(aP + 32, &As[0][2 * w + 1][0]);
    gl2lds16(qP,      &Bq[0][2 * w    ][0]);
    gl2lds16(qP + 32, &Bq[0][2 * w + 1][0]);
    gl2lds16(kP,      &Bk[0][2 * w    ][0]);
    gl2lds16(kP + 32, &Bk[0][2 * w + 1][0]);
    gl2lds16(vP,      &Bv[0][2 * w    ][0]);
    gl2lds16(vP + 32, &Bv[0][2 * w + 1][0]);
    gl2lds16(kP + 64, &Bk[1][2 * w    ][0]);
    gl2lds16(kP + 96, &Bk[1][2 * w + 1][0]);
    gl2lds16(vP + 64, &Bv[1][2 * w    ][0]);
    gl2lds16(vP + 96, &Bv[1][2 * w + 1][0]);
    asm volatile("s_waitcnt vmcnt(4)" ::: "memory");   // tile 0 landed
    __builtin_amdgcn_s_barrier();

    bf16x8 ap[4][2], fq[2][2], fk[2][2], fv[2][2];

    for (int kt = 0; kt < NTQ; ++kt) {
        const int cur = kt & 1;
        const int ko  = kt * 64;

        // ds_read 20 frags from buf[cur]
#pragma unroll
        for (int mi = 0; mi < 4; ++mi)
#pragma unroll
            for (int ks = 0; ks < 2; ++ks)
                ap[mi][ks] = *(const bf16x8*)&As[cur][(wm4 + mi) * 2 + ks][lane8];
#pragma unroll
        for (int nj = 0; nj < 2; ++nj)
#pragma unroll
            for (int ks = 0; ks < 2; ++ks) {
                fq[nj][ks] = *(const bf16x8*)&Bq[cur][(wn2 + nj) * 2 + ks][lane8];
                fk[nj][ks] = *(const bf16x8*)&Bk[cur][(wn2 + nj) * 2 + ks][lane8];
                fv[nj][ks] = *(const bf16x8*)&Bv[cur][(wn2 + nj) * 2 + ks][lane8];
            }

        // pre-barrier: stage kt+1 {A, Bq} -> buf^1 (portions consumed at kt-1)
        if (kt + 1 < NTQ) {
            gl2lds16(aP + ko + 64, &As[cur ^ 1][2 * w    ][0]);
            gl2lds16(aP + ko + 96, &As[cur ^ 1][2 * w + 1][0]);
            gl2lds16(qP + ko + 64, &Bq[cur ^ 1][2 * w    ][0]);
            gl2lds16(qP + ko + 96, &Bq[cur ^ 1][2 * w + 1][0]);
        }

        __builtin_amdgcn_s_barrier();
        asm volatile("s_waitcnt lgkmcnt(0)" ::: "memory");

        // post-lgkm: stage kt+2 {Bk,Bv} -> buf[cur] (R14-validated ordering)
        if (kt + 2 < NTQ) {
            gl2lds16(kP + ko + 128, &Bk[cur][2 * w    ][0]);
            gl2lds16(kP + ko + 160, &Bk[cur][2 * w + 1][0]);
            gl2lds16(vP + ko + 128, &Bv[cur][2 * w    ][0]);
            gl2lds16(vP + ko + 160, &Bv[cur][2 * w + 1][0]);
        }

        __builtin_amdgcn_s_setprio(1);
#pragma unroll
        for (int mi = 0; mi < 4; ++mi)
#pragma unroll
            for (int nj = 0; nj < 2; ++nj) {
#pragma unroll
                for (int ks = 0; ks < 2; ++ks)
                    aq[mi][nj] = __builtin_amdgcn_mfma_f32_16x16x32_bf16(
                        fq[nj][ks], ap[mi][ks], aq[mi][nj], 0, 0, 0);
#pragma unroll
                for (int ks = 0; ks < 2; ++ks)
                    ak[mi][nj] = __builtin_amdgcn_mfma_f32_16x16x32_bf16(
                        fk[nj][ks], ap[mi][ks], ak[mi][nj], 0, 0, 0);
#pragma unroll
                for (int ks = 0; ks < 2; ++ks)
                    av[mi][nj] = __builtin_amdgcn_mfma_f32_16x16x32_bf16(
                        ap[mi][ks], fv[nj][ks], av[mi][nj], 0, 0, 0);
            }
        __builtin_amdgcn_s_setprio(0);

        if (kt < NTQ - 2)       asm volatile("s_waitcnt vmcnt(4)" ::: "memory");
        else if (kt == NTQ - 2) asm volatile("s_waitcnt vmcnt(0)" ::: "memory");
        __builtin_amdgcn_s_barrier();
    }

    // ---- epilogue: Q (scaled), K -> [bh][t][dk]; V -> V^T [bh][dk][t] ----
    const int mbase = m0 + (w >> 2) * 64;
    const int nbase = n0 + (w & 3) * 32;
    const size_t BTD = (size_t)B_ * T_ * D_;
    const float osc = 0.125f * 1.44269504f;

#pragma unroll
    for (int nj = 0; nj < 2; ++nj) {
        const int ch0 = nbase + nj * 16 + g * 4;
        const int hh = ch0 >> 6, dk0 = ch0 & 63;
        const float4 bbq = *(const float4*)(bq + ch0);
        const float4 bbk = *(const float4*)(bk + ch0);
#pragma unroll
        for (int mi = 0; mi < 4; ++mi) {
            const int tok = mbase + mi * 16 + l15;
            const int b = tok >> 11, t = tok & (T_ - 1);
            const size_t base = ((size_t)((b * H_ + hh) * T_ + t)) * DK_ + dk0;
            ushort4 rq, rk;
            rq.x = f2bf((aq[mi][nj][0] + bbq.x) * osc);
            rq.y = f2bf((aq[mi][nj][1] + bbq.y) * osc);
            rq.z = f2bf((aq[mi][nj][2] + bbq.z) * osc);
            rq.w = f2bf((aq[mi][nj][3] + bbq.w) * osc);
            rk.x = f2bf(ak[mi][nj][0] + bbk.x);
            rk.y = f2bf(ak[mi][nj][1] + bbk.y);
            rk.z = f2bf(ak[mi][nj][2] + bbk.z);
            rk.w = f2bf(ak[mi][nj][3] + bbk.w);
            *(ushort4*)(outU + base) = rq;
            *(ushort4*)(outU + BTD + base) = rk;
        }
    }
    {
        unsigned short* outv = outU + 2 * BTD;
#pragma unroll
        for (int nj = 0; nj < 2; ++nj) {
            const int ch = nbase + nj * 16 + l15;
            const int hh = ch >> 6, dk = ch & 63;
            const float bbv = bv[ch];
#pragma unroll
            for (int mi = 0; mi < 4; ++mi) {
                const int tok0 = mbase + mi * 16 + g * 4;
                const int b = tok0 >> 11, t0 = tok0 & (T_ - 1);
                ushort4 r;
                r.x = f2bf(av[mi][nj][0] + bbv);
                r.y = f2bf(av[mi][nj][1] + bbv);
                r.z = f2bf(av[mi][nj][2] + bbv);
                r.w = f2bf(av[mi][nj][3] + bbv);
                *(ushort4*)(outv + ((size_t)((b * H_ + hh) * DK_ + dk)) * T_ + t0) = r;
            }
        }
    }
}

// ---------------------------------------------------------------------------
// 256(M)x128(N) BK=64 MFMA GEMM (R3 structure, frozen) — out-proj (mode 1).
// ---------------------------------------------------------------------------
__global__ __launch_bounds__(512, 2) void gemm8p(
    const unsigned short* __restrict__ Amat,
    const unsigned short* __restrict__ w0,
    const unsigned short* __restrict__ w1,
    const unsigned short* __restrict__ w2,
    const float* __restrict__ b0,
    const float* __restrict__ b1,
    const float* __restrict__ b2,
    unsigned short* __restrict__ outU,
    float* __restrict__ outF,
    const int mode)
{
    const int s   = blockIdx.x;
    const int xcd = s & 7;
    const int idx = s >> 3;
    const int mm  = idx & 3;
    const int ns  = idx >> 2;
    const int sel = (mode == 0) ? (ns >> 3) : 3;
    const int nn  = (mode == 0) ? (ns & 7) : ns;
    const int m0  = (xcd * 4 + mm) * 256;
    const int n0  = nn * 128;

    const unsigned short* Bmat = (sel == 0) ? w0 : (sel == 1) ? w1 : w2;
    const float* bias          = (sel == 0) ? b0 : (sel == 1) ? b1 : b2;
    const bool selV = (sel == 2);

    const int tid  = threadIdx.x;
    const int w    = tid >> 6;
    const int lane = tid & 63;
    const int l15  = lane & 15, g = lane >> 4;
    const int lane8 = lane * 8;
    const int wm8  = (w >> 2) * 8;
    const int wn2  = (w & 3) * 2;

    __shared__ __align__(16) unsigned short As[2][32][512];   // 64 KB
    __shared__ __align__(16) unsigned short Bs[2][16][512];   // 32 KB

    f32x4 acc[8][2];
#pragma unroll
    for (int i = 0; i < 8; ++i)
#pragma unroll
        for (int j = 0; j < 2; ++j) acc[i][j] = (f32x4){0.f, 0.f, 0.f, 0.f};

    const unsigned short* aP[4];
#pragma unroll
    for (int j = 0; j < 4; ++j)
        aP[j] = Amat + (size_t)(m0 + (w >> 1) * 16 + 64 * j + l15) * D_
                     + (w & 1) * 32 + g * 8;
    const unsigned short* bP[2];
#pragma unroll
    for (int jb = 0; jb < 2; ++jb)
        bP[jb] = Bmat + (size_t)(n0 + w * 16 + l15) * D_ + jb * 32 + g * 8;

#pragma unroll
    for (int j = 0; j < 4; ++j) gl2lds16(aP[j], &As[0][w + 8 * j][0]);
    gl2lds16(bP[0], &Bs[0][2 * w    ][0]);
    gl2lds16(bP[1], &Bs[0][2 * w + 1][0]);
    gl2lds16(aP[0] + 64, &As[1][w     ][0]);
    gl2lds16(aP[2] + 64, &As[1][w + 16][0]);
    gl2lds16(bP[0] + 64, &Bs[1][2 * w    ][0]);
    gl2lds16(bP[1] + 64, &Bs[1][2 * w + 1][0]);
    asm volatile("s_waitcnt vmcnt(4)" ::: "memory");
    __builtin_amdgcn_s_barrier();

    bf16x8 bfr[2][2];
    bf16x8 ap[4][2];

    for (int kt = 0; kt < NT8; ++kt) {
        const int cur = kt & 1;
        const int ko  = kt * 64;

#pragma unroll
        for (int nj = 0; nj < 2; ++nj)
#pragma unroll
            for (int ks = 0; ks < 2; ++ks)
                bfr[nj][ks] = *(const bf16x8*)&Bs[cur][(wn2 + nj) * 2 + ks][lane8];
#pragma unroll
        for (int mi = 0; mi < 4; ++mi)
#pragma unroll
            for (int ks = 0; ks < 2; ++ks)
                ap[mi][ks] = *(const bf16x8*)&As[cur][(wm8 + mi) * 2 + ks][lane8];
        if (kt + 1 < NT8) {
            gl2lds16(aP[1] + ko + 64, &As[cur ^ 1][w + 8 ][0]);
            gl2lds16(aP[3] + ko + 64, &As[cur ^ 1][w + 24][0]);
        }
        __builtin_amdgcn_s_barrier();
        asm volatile("s_waitcnt lgkmcnt(0)" ::: "memory");
        __builtin_amdgcn_s_setprio(1);
        if (!selV) {
#pragma unroll
            for (int mi = 0; mi < 4; ++mi)
#pragma unroll
                for (int nj = 0; nj < 2; ++nj) {
                    acc[mi][nj] = __builtin_amdgcn_mfma_f32_16x16x32_bf16(
                        bfr[nj][0], ap[mi][0], acc[mi][nj], 0, 0, 0);
                    acc[mi][nj] = __builtin_amdgcn_mfma_f32_16x16x32_bf16(
                        bfr[nj][1], ap[mi][1], acc[mi][nj], 0, 0, 0);
                }
        } else {
#pragma unroll
            for (int mi = 0; mi < 4; ++mi)
#pragma unroll
                for (int nj = 0; nj < 2; ++nj) {
                    acc[mi][nj] = __builtin_amdgcn_mfma_f32_16x16x32_bf16(
                        ap[mi][0], bfr[nj][0], acc[mi][nj], 0, 0, 0);
                    acc[mi][nj] = __builtin_amdgcn_mfma_f32_16x16x32_bf16(
                        ap[mi][1], bfr[nj][1], acc[mi][nj], 0, 0, 0);
                }
        }
        __builtin_amdgcn_s_setprio(0);
        __builtin_amdgcn_s_barrier();

#pragma unroll
        for (int mi = 0; mi < 4; ++mi)
#pragma unroll
            for (int ks = 0; ks < 2; ++ks)
                ap[mi][ks] = *(const bf16x8*)&As[cur][(wm8 + 4 + mi) * 2 + ks][lane8];
        if (kt + 2 < NT8) {
            gl2lds16(aP[0] + ko + 128, &As[cur][w     ][0]);
            gl2lds16(aP[2] + ko + 128, &As[cur][w + 16][0]);
            gl2lds16(bP[0] + ko + 128, &Bs[cur][2 * w    ][0]);
            gl2lds16(bP[1] + ko + 128, &Bs[cur][2 * w + 1][0]);
        }
        __builtin_amdgcn_s_barrier();
        asm volatile("s_waitcnt lgkmcnt(0)" ::: "memory");
        __builtin_amdgcn_s_setprio(1);
        if (!selV) {
#pragma unroll
            for (int mi = 0; mi < 4; ++mi)
#pragma unroll
                for (int nj = 0; nj < 2; ++nj) {
                    acc[4 + mi][nj] = __builtin_amdgcn_mfma_f32_16x16x32_bf16(
                        bfr[nj][0], ap[mi][0], acc[4 + mi][nj], 0, 0, 0);
                    acc[4 + mi][nj] = __builtin_amdgcn_mfma_f32_16x16x32_bf16(
                        bfr[nj][1], ap[mi][1], acc[4 + mi][nj], 0, 0, 0);
                }
        } else {
#pragma unroll
            for (int mi = 0; mi < 4; ++mi)
#pragma unroll
                for (int nj = 0; nj < 2; ++nj) {
                    acc[4 + mi][nj] = __builtin_amdgcn_mfma_f32_16x16x32_bf16(
                        ap[mi][0], bfr[nj][0], acc[4 + mi][nj], 0, 0, 0);
                    acc[4 + mi][nj] = __builtin_amdgcn_mfma_f32_16x16x32_bf16(
                        ap[mi][1], bfr[nj][1], acc[4 + mi][nj], 0, 0, 0);
                }
        }
        __builtin_amdgcn_s_setprio(0);
        if (kt < NT8 - 2)       asm volatile("s_waitcnt vmcnt(4)" ::: "memory");
        else if (kt == NT8 - 2) asm volatile("s_waitcnt vmcnt(0)" ::: "memory");
        __builtin_amdgcn_s_barrier();
    }

    const int mbase = m0 + (w >> 2) * 128;
    const int nbase = n0 + (w & 3) * 32;
    const size_t BTD = (size_t)B_ * T_ * D_;

    if (mode == 1) {
#pragma unroll
        for (int nj = 0; nj < 2; ++nj) {
            const int ch0 = nbase + nj * 16 + g * 4;
            const float4 bb = *(const float4*)(bias + ch0);
#pragma unroll
            for (int mi = 0; mi < 8; ++mi) {
                const int tok = mbase + mi * 16 + l15;
                float4 r;
                r.x = acc[mi][nj][0] + bb.x;
                r.y = acc[mi][nj][1] + bb.y;
                r.z = acc[mi][nj][2] + bb.z;
                r.w = acc[mi][nj][3] + bb.w;
                *(float4*)(outF + (size_t)tok * D_ + ch0) = r;
            }
        }
    } else if (!selV) {
        unsigned short* outp = outU + (size_t)sel * BTD;
        const float osc = (sel == 0) ? 0.125f * 1.44269504f : 1.0f;
#pragma unroll
        for (int nj = 0; nj < 2; ++nj) {
            const int ch0 = nbase + nj * 16 + g * 4;
            const int hh = ch0 >> 6, dk0 = ch0 & 63;
            const float4 bb = *(const float4*)(bias + ch0);
#pragma unroll
            for (int mi = 0; mi < 8; ++mi) {
                const int tok = mbase + mi * 16 + l15;
                const int b = tok >> 11, t = tok & (T_ - 1);
                ushort4 r;
                r.x = f2bf((acc[mi][nj][0] + bb.x) * osc);
                r.y = f2bf((acc[mi][nj][1] + bb.y) * osc);
                r.z = f2bf((acc[mi][nj][2] + bb.z) * osc);
                r.w = f2bf((acc[mi][nj][3] + bb.w) * osc);
                *(ushort4*)(outp + ((size_t)((b * H_ + hh) * T_ + t)) * DK_ + dk0) = r;
            }
        }
    } else {
        unsigned short* outp = outU + 2 * BTD;
#pragma unroll
        for (int nj = 0; nj < 2; ++nj) {
            const int ch = nbase + nj * 16 + l15;
            const int hh = ch >> 6, dk = ch & 63;
            const float bbv = bias[ch];
#pragma unroll
            for (int mi = 0; mi < 8; ++mi) {
                const int tok0 = mbase + mi * 16 + g * 4;
                const int b = tok0 >> 11, t0 = tok0 & (T_ - 1);
                ushort4 r;
                r.x = f2bf(acc[mi][nj][0] + bbv);
                r.y = f2bf(acc[mi][nj][1] + bbv);
                r.z = f2bf(acc[mi][nj][2] + bbv);
                r.w = f2bf(acc[mi][nj][3] + bbv);
                *(ushort4*)(outp + ((size_t)((b * H_ + hh) * DK_ + dk)) * T_ + t0) = r;
            }
        }
    }
}

// ---------------------------------------------------------------------------
// MFMA flash attention — R8 body, R16 dispatch order: rank-major
// (j = t_>>3 heavy rank, bhl = t_&7). Initially-resident blocks on a CU now
// span j values spaced by 4 (mixed heavy/light) instead of one rank across
// six bh — fixes the work-clumping that held time-avg occupancy at 30%.
// Still globally heavy-first (all x=31 blocks dispatch first), light tail.
// ---------------------------------------------------------------------------
__global__ __launch_bounds__(256) void attn(
    const unsigned short* __restrict__ qg, const unsigned short* __restrict__ kg,
    const unsigned short* __restrict__ vtg,
    unsigned short* __restrict__ yh)
{
    const int s    = blockIdx.x;          // 0..2047
    const int xcd  = s & 7;
    const int t_   = s >> 3;              // 0..255
    const int j    = t_ >> 3;             // 0..31  heavy rank (fast-varying CU mix)
    const int bhl  = t_ & 7;              // 0..7
    const int bh   = xcd * 8 + bhl;
    const int x    = 31 - j;              // heavy-first
    const int h    = bh & (H_ - 1);
    const int b    = bh >> 4;
    const int tq0  = x * 64;
    const int nCh  = x + 1;               // keys 0..tq0+63, 64-wide chunks

    const int tid  = threadIdx.x;
    const int w    = tid >> 6;
    const int lane = tid & 63;
    const int l15  = lane & 15;
    const int g    = lane >> 4;

    const size_t base = (size_t)bh * T_ * DK_;
    const unsigned short* Qb  = qg  + base;   // [t][dk], pre-scaled
    const unsigned short* Kb  = kg  + base;   // [t][dk]
    const unsigned short* Vtb = vtg + base;   // [dk][t]

    __shared__ __align__(16) unsigned short Kf[8][512];     // 8 KB
    __shared__ __align__(16) unsigned short Vf[8][512];     // 8 KB
    __shared__ __align__(16) unsigned short Pb[4][16][68];  // 8.7 KB

    const int q0w = tq0 + w * 16;
    const int tq  = q0w + l15;

    bf16x8 qf0 = *(const bf16x8*)(Qb + (size_t)tq * DK_ + g * 8);
    bf16x8 qf1 = *(const bf16x8*)(Qb + (size_t)tq * DK_ + 32 + g * 8);

    bf16x8 ones;
#pragma unroll
    for (int jj = 0; jj < 8; ++jj) ones[jj] = (short)0x3F80;

    f32x4 o[4];
#pragma unroll
    for (int i = 0; i < 4; ++i) o[i] = (f32x4){0.f, 0.f, 0.f, 0.f};
    f32x4 lacc = {0.f, 0.f, 0.f, 0.f};

    const unsigned short* kSrc = Kb + (size_t)(w * 16 + l15) * DK_ + g * 8;
    const unsigned short* vSrc = Vtb + (size_t)(w * 16 + l15) * T_ + g * 8;

    bf16x8 kr0 = *(const bf16x8*)(kSrc);
    bf16x8 kr1 = *(const bf16x8*)(kSrc + 32);
    bf16x8 vr0 = *(const bf16x8*)(vSrc);
    bf16x8 vr1 = *(const bf16x8*)(vSrc + 32);

    for (int ch = 0; ch < nCh; ++ch) {
        const int s0 = ch * 64;
        __syncthreads();                       // previous chunk fully consumed
        *(bf16x8*)&Kf[2 * w    ][lane * 8] = kr0;
        *(bf16x8*)&Kf[2 * w + 1][lane * 8] = kr1;
        *(bf16x8*)&Vf[2 * w    ][lane * 8] = vr0;
        *(bf16x8*)&Vf[2 * w + 1][lane * 8] = vr1;
        if (ch + 1 < nCh) {                    // loads stay in flight across barrier
            const size_t ko = (size_t)(ch + 1) * 64 * DK_;
            const int    vo = (ch + 1) * 64;
            kr0 = *(const bf16x8*)(kSrc + ko);
            kr1 = *(const bf16x8*)(kSrc + ko + 32);
            vr0 = *(const bf16x8*)(vSrc + vo);
            vr1 = *(const bf16x8*)(vSrc + vo + 32);
        }
        __syncthreads();                       // staged data visible

#pragma unroll
        for (int st = 0; st < 4; ++st) {
            const int sbase = s0 + st * 16;
            const bool live = (sbase <= q0w + 15);
            unsigned int pkl, pkh;
            if (live) {
                bf16x8 a0 = *(const bf16x8*)&Kf[st * 2 + 0][lane * 8];
                bf16x8 a1 = *(const bf16x8*)&Kf[st * 2 + 1][lane * 8];
                f32x4 sacc = {0.f, 0.f, 0.f, 0.f};
                sacc = __builtin_amdgcn_mfma_f32_16x16x32_bf16(a0, qf0, sacc, 0, 0, 0);
                sacc = __builtin_amdgcn_mfma_f32_16x16x32_bf16(a1, qf1, sacc, 0, 0, 0);
                float p0, p1, p2, p3;
                if (sbase + 15 > q0w) {        // diagonal tile: per-entry mask
                    p0 = (sbase + g * 4 + 0 <= tq) ? exp2f(sacc[0]) : 0.f;
                    p1 = (sbase + g * 4 + 1 <= tq) ? exp2f(sacc[1]) : 0.f;
                    p2 = (sbase + g * 4 + 2 <= tq) ? exp2f(sacc[2]) : 0.f;
                    p3 = (sbase + g * 4 + 3 <= tq) ? exp2f(sacc[3]) : 0.f;
                } else {                       // fully unmasked
                    p0 = exp2f(sacc[0]); p1 = exp2f(sacc[1]);
                    p2 = exp2f(sacc[2]); p3 = exp2f(sacc[3]);
                }
                pkl = pk2bf(p0, p1);
                pkh = pk2bf(p2, p3);
            } else {
                pkl = 0; pkh = 0;
            }
            uint2 pk; pk.x = pkl; pk.y = pkh;
            *(uint2*)&Pb[w][l15][st * 16 + g * 4] = pk;     // P[q][s], s-contig
        }

        bf16x8 pf0 = *(const bf16x8*)&Pb[w][l15][g * 8];        // k = s 0..31
        bf16x8 pf1 = *(const bf16x8*)&Pb[w][l15][32 + g * 8];   // k = s 32..63
        __builtin_amdgcn_s_setprio(1);
        lacc = __builtin_amdgcn_mfma_f32_16x16x32_bf16(ones, pf0, lacc, 0, 0, 0);
        lacc = __builtin_amdgcn_mfma_f32_16x16x32_bf16(ones, pf1, lacc, 0, 0, 0);
#pragma unroll
        for (int dt = 0; dt < 4; ++dt) {
            bf16x8 v0 = *(const bf16x8*)&Vf[dt * 2 + 0][lane * 8];
            bf16x8 v1 = *(const bf16x8*)&Vf[dt * 2 + 1][lane * 8];
            o[dt] = __builtin_amdgcn_mfma_f32_16x16x32_bf16(v0, pf0, o[dt], 0, 0, 0);
            o[dt] = __builtin_amdgcn_mfma_f32_16x16x32_bf16(v1, pf1, o[dt], 0, 0, 0);
        }
        __builtin_amdgcn_s_setprio(0);
    }

    // normalize and write yh bf16 directly (always single-pass)
    const float inv = 1.f / lacc[0];
    unsigned short* yrow = yh + ((size_t)(b * T_ + tq)) * D_ + h * DK_;
#pragma unroll
    for (int dt = 0; dt < 4; ++dt) {
        ushort4 r;
        r.x = f2bf(o[dt][0] * inv); r.y = f2bf(o[dt][1] * inv);
        r.z = f2bf(o[dt][2] * inv); r.w = f2bf(o[dt][3] * inv);
        *(ushort4*)(yrow + dt * 16 + g * 4) = r;
    }
}

// ---------------------------------------------------------------------------
extern "C" void kernel_launch(void* const* d_in, const int* in_sizes, int n_in,
                              void* d_out, int out_size, void* d_ws, size_t ws_size,
                              hipStream_t stream) {
    const float* x  = (const float*)d_in[0];
    const float* wq = (const float*)d_in[1];
    const float* bq = (const float*)d_in[2];
    const float* wk = (const float*)d_in[3];
    const float* bk = (const float*)d_in[4];
    const float* wv = (const float*)d_in[5];
    const float* bv = (const float*)d_in[6];
    const float* wo = (const float*)d_in[7];
    const float* bo = (const float*)d_in[8];
    float* out = (float*)d_out;

    const size_t BTD = (size_t)B_ * T_ * D_;          // 8388608
    const size_t WSZ = (size_t)D_ * D_;               // 1048576
    unsigned short* xb  = (unsigned short*)d_ws;      // [x | wq | wk | wv | wo] bf16
    unsigned short* wqb = xb  + BTD;
    unsigned short* wkb = wqb + WSZ;
    unsigned short* wvb = wkb + WSZ;
    unsigned short* wob = wvb + WSZ;
    unsigned short* qb  = wob + WSZ;                  // q | k | vt bf16
    unsigned short* kb  = qb  + BTD;
    unsigned short* vtb = kb  + BTD;
    unsigned short* yhb = vtb + BTD;                  // yh bf16 [B,T,D]

    cvt_bf16<<<dim3(12288), 256, 0, stream>>>(x, wq, wk, wv, wo, xb);

    // fused QKV: 8 xcd x 8 m x 8 n = 512 blocks = 2 exact rounds @1/CU
    qkv_fused<<<dim3(512), 512, 0, stream>>>(
        xb, wqb, wkb, wvb, bq, bk, bv, qb);

    // attn: 2048 blocks (32 per bh), XCD-pinned, rank-major heavy-first
    attn<<<dim3(2048), 256, 0, stream>>>(qb, kb, vtb, yhb);

    // out-proj: 8 x 4 x 8 = 256 blocks = exactly 1 round (R3 gemm, frozen)
    gemm8p<<<dim3(256), 512, 0, stream>>>(
        yhb, wob, wob, wob, bo, bo, bo, (unsigned short*)nullptr, out, 1);
}